// Round 1
// baseline (1129.752 us; speedup 1.0000x reference)
//
#include <hip/hip_runtime.h>
#include <hip/hip_bf16.h>

#define N_NODES 51200
#define N_EDGES 819200
#define N_GRAPHS 256

// ---------------------------------------------------------------------------
// k_zero: zero hg accumulator + dst-degree counters (must re-zero every call)
// ---------------------------------------------------------------------------
__global__ void k_zero(float* __restrict__ hg, int* __restrict__ cnt) {
    int i = blockIdx.x * blockDim.x + threadIdx.x;
    if (i < N_GRAPHS * 49) hg[i] = 0.f;
    if (i < N_NODES) cnt[i] = 0;
}

// ---------------------------------------------------------------------------
// k_count: histogram of dst
// ---------------------------------------------------------------------------
__global__ void k_count(const int* __restrict__ dst, int* __restrict__ cnt) {
    int e = blockIdx.x * blockDim.x + threadIdx.x;
    if (e < N_EDGES) atomicAdd(&cnt[dst[e]], 1);
}

// ---------------------------------------------------------------------------
// k_scan: single-block exclusive scan -> row_ptr[N+1], cursor[N]
// ---------------------------------------------------------------------------
__global__ __launch_bounds__(1024) void k_scan(const int* __restrict__ cnt,
                                               int* __restrict__ row_ptr,
                                               int* __restrict__ cursor) {
    __shared__ int s[1024];
    int tid = threadIdx.x;
    if (tid == 0) row_ptr[0] = 0;
    int running = 0;
    for (int base = 0; base < N_NODES; base += 1024) {
        int idx = base + tid;
        int v = (idx < N_NODES) ? cnt[idx] : 0;
        s[tid] = v;
        __syncthreads();
        for (int off = 1; off < 1024; off <<= 1) {
            int t = s[tid];
            if (tid >= off) t += s[tid - off];
            __syncthreads();
            s[tid] = t;
            __syncthreads();
        }
        int incl = s[tid];
        int total = s[1023];
        if (idx < N_NODES) {
            row_ptr[idx + 1] = running + incl;
            cursor[idx]      = running + incl - v;   // exclusive = row start
        }
        running += total;
        __syncthreads();
    }
}

// ---------------------------------------------------------------------------
// k_scatter: bucket edges by dst (CSR). Order within a row is nondeterministic
// (atomic), only perturbs fp sum order ~1e-6 — far under threshold.
// ---------------------------------------------------------------------------
__global__ void k_scatter(const int* __restrict__ src, const int* __restrict__ dst,
                          const float* __restrict__ ew,
                          int* __restrict__ cursor,
                          int* __restrict__ s_src, float* __restrict__ s_w) {
    int e = blockIdx.x * blockDim.x + threadIdx.x;
    if (e < N_EDGES) {
        int pos = atomicAdd(&cursor[dst[e]], 1);
        s_src[pos] = src[e];
        s_w[pos]   = ew[e];
    }
}

// ---------------------------------------------------------------------------
// k_conv: fused 3x dilated conv1d over node axis + h01/h02/h03 build +
//         epilogue GEMM with W11/W12/W13 -> hw_cat [N][162]
// Block: 256 threads = 4 waves. lanes = 64 nodes of the tile; wave w owns
// output channels [24w, 24w+24). Weight reads are wave-uniform -> scalar.
// ---------------------------------------------------------------------------
#define BN 64
__global__ __launch_bounds__(256) void k_conv(
    const float* __restrict__ x,
    const float* __restrict__ w1, const float* __restrict__ b1,
    const float* __restrict__ w2, const float* __restrict__ b2,
    const float* __restrict__ w3, const float* __restrict__ b3,
    const float* __restrict__ W11, const float* __restrict__ W12,
    const float* __restrict__ W13,
    float* __restrict__ hw_cat) {
    __shared__ float xs[(BN + 6) * 129];   // 70 rows x 128, stride 129 (bank-safe)
    __shared__ float hs[BN * 97];          // transpose / GEMM staging buffer

    const int tid = threadIdx.x;
    const int n0  = blockIdx.x * BN;

    // stage x rows [n0-3, n0+BN+3), zero-padded at the ends
    for (int idx = tid; idx < (BN + 6) * 32; idx += 256) {
        int row = idx >> 5, c4 = (idx & 31) * 4;
        int node = n0 - 3 + row;
        float4 v = make_float4(0.f, 0.f, 0.f, 0.f);
        if (node >= 0 && node < N_NODES)
            v = *reinterpret_cast<const float4*>(x + (size_t)node * 128 + c4);
        xs[row * 129 + c4 + 0] = v.x;
        xs[row * 129 + c4 + 1] = v.y;
        xs[row * 129 + c4 + 2] = v.z;
        xs[row * 129 + c4 + 3] = v.w;
    }
    __syncthreads();

    const int lane  = tid & 63;
    const int wave  = __builtin_amdgcn_readfirstlane(tid >> 6);
    const int obase = wave * 24;
    const int srow  = lane + 3;

    float acc1[24], acc2[24], acc3[24];
#pragma unroll
    for (int o = 0; o < 24; ++o) acc1[o] = acc2[o] = acc3[o] = 0.f;

    for (int i = 0; i < 128; ++i) {
        float xr[7];
#pragma unroll
        for (int r = 0; r < 7; ++r) xr[r] = xs[(srow - 3 + r) * 129 + i];
#pragma unroll
        for (int oo = 0; oo < 24; ++oo) {
            int o = obase + oo;
            const float* p1 = w1 + o * 384 + i * 3;
            const float* p2 = w2 + o * 384 + i * 3;
            const float* p3 = w3 + o * 384 + i * 3;
            // dilation d taps at xr[3-d], xr[3], xr[3+d]
            acc1[oo] += xr[2] * p1[0] + xr[3] * p1[1] + xr[4] * p1[2];
            acc2[oo] += xr[1] * p2[0] + xr[3] * p2[1] + xr[5] * p2[2];
            acc3[oo] += xr[0] * p3[0] + xr[3] * p3[1] + xr[6] * p3[2];
        }
    }

    // h01 = relu(c1)+c2 ; h02 = relu(c2)+c3 ; h03 = relu(c3)+c1  (in-place)
#pragma unroll
    for (int oo = 0; oo < 24; ++oo) {
        int o = obase + oo;
        float c1 = acc1[oo] + b1[o];
        float c2 = acc2[oo] + b2[o];
        float c3 = acc3[oo] + b3[o];
        acc1[oo] = fmaxf(c1, 0.f) + c2;
        acc2[oo] = fmaxf(c2, 0.f) + c3;
        acc3[oo] = fmaxf(c3, 0.f) + c1;
    }

    // epilogue: hw_cat[:, 54k : 54k+54] = h0k @ W1k
    auto do_branch = [&](int k, float (&hv)[24], const float* __restrict__ W) {
        __syncthreads();
#pragma unroll
        for (int oo = 0; oo < 24; ++oo) hs[lane * 97 + obase + oo] = hv[oo];
        __syncthreads();
        int jb = wave < 2 ? wave * 14 : 28 + (wave - 2) * 13;
        int jl = wave < 2 ? 14 : 13;
        float acc[14];
#pragma unroll
        for (int j = 0; j < 14; ++j) acc[j] = 0.f;
        for (int i = 0; i < 96; ++i) {
            float hval = hs[lane * 97 + i];
#pragma unroll
            for (int j = 0; j < 14; ++j)
                if (j < jl) acc[j] += hval * W[i * 54 + jb + j];
        }
        __syncthreads();
#pragma unroll
        for (int j = 0; j < 14; ++j)
            if (j < jl) hs[lane * 55 + jb + j] = acc[j];
        __syncthreads();
        for (int idx = tid; idx < BN * 54; idx += 256) {
            int r = idx / 54, c = idx - r * 54;
            hw_cat[(size_t)(n0 + r) * 162 + k * 54 + c] = hs[r * 55 + c];
        }
    };
    do_branch(0, acc1, W11);
    do_branch(1, acc2, W12);
    do_branch(2, acc3, W13);
}

// ---------------------------------------------------------------------------
// k_agg1: CSR aggregate of hw_cat (3x54) -> ac_h1 = sum_k relu(agg_k + b1k)
// one wave per dst node, lanes = features
// ---------------------------------------------------------------------------
__global__ __launch_bounds__(256) void k_agg1(
    const float* __restrict__ hw_cat, const int* __restrict__ row_ptr,
    const int* __restrict__ s_src, const float* __restrict__ s_w,
    const float* __restrict__ b11, const float* __restrict__ b12,
    const float* __restrict__ b13, float* __restrict__ ac_h1) {
    int tid = threadIdx.x;
    int lane = tid & 63, wave = tid >> 6;
    int n = blockIdx.x * 4 + wave;
    int e0 = row_ptr[n], e1 = row_ptr[n + 1];
    float a0 = 0.f, a1 = 0.f, a2 = 0.f;
    for (int e = e0; e < e1; ++e) {
        int s  = s_src[e];
        float w = s_w[e];
        const float* p = hw_cat + (size_t)s * 162;
        if (lane < 54) {
            a0 += w * p[lane];
            a1 += w * p[54 + lane];
            a2 += w * p[108 + lane];
        }
    }
    if (lane < 54) {
        float v = fmaxf(a0 + b11[lane], 0.f) + fmaxf(a1 + b12[lane], 0.f) +
                  fmaxf(a2 + b13[lane], 0.f);
        ac_h1[(size_t)n * 54 + lane] = v;
    }
}

// ---------------------------------------------------------------------------
// k_g2: hw2 = ac_h1 @ W2   [N,54]x[54,25]
// ---------------------------------------------------------------------------
__global__ __launch_bounds__(256) void k_g2(const float* __restrict__ ac_h1,
                                            const float* __restrict__ W2,
                                            float* __restrict__ hw2) {
    __shared__ float xls[128 * 56];
    int tid = threadIdx.x;
    int n0 = blockIdx.x * 128;
    for (int idx = tid; idx < 128 * 56; idx += 256) {
        int r = idx / 56, c = idx - r * 56;
        xls[idx] = (c < 54) ? ac_h1[(size_t)(n0 + r) * 54 + c] : 0.f;
    }
    __syncthreads();
    int j = tid & 31;
    int g = tid >> 5;
    int rbase = g * 16;
    float acc[16];
#pragma unroll
    for (int r = 0; r < 16; ++r) acc[r] = 0.f;
    if (j < 25) {
        for (int i = 0; i < 54; ++i) {
            float w = W2[i * 25 + j];
#pragma unroll
            for (int rr = 0; rr < 16; ++rr)
                acc[rr] += xls[(rbase + rr) * 56 + i] * w;
        }
#pragma unroll
        for (int rr = 0; rr < 16; ++rr)
            hw2[(size_t)(n0 + rbase + rr) * 25 + j] = acc[rr];
    }
}

// ---------------------------------------------------------------------------
// k_agg2: aggregate hw2 -> ac_h2 = relu(agg + b2); also seg-sum into hg[:,0:25]
// two dst nodes per wave (lanes 0..24 / 32..56)
// ---------------------------------------------------------------------------
__global__ __launch_bounds__(256) void k_agg2(
    const float* __restrict__ hw2, const int* __restrict__ row_ptr,
    const int* __restrict__ s_src, const float* __restrict__ s_w,
    const float* __restrict__ b2, const int* __restrict__ gids,
    float* __restrict__ ac_h2, float* __restrict__ hg) {
    int tid = threadIdx.x;
    int lane = tid & 63, wave = tid >> 6;
    int half = lane >> 5, jj = lane & 31;
    int n = blockIdx.x * 8 + wave * 2 + half;
    int e0 = row_ptr[n], e1 = row_ptr[n + 1];
    float acc = 0.f;
    for (int e = e0; e < e1; ++e) {
        int s  = s_src[e];
        float w = s_w[e];
        if (jj < 25) acc += w * hw2[(size_t)s * 25 + jj];
    }
    if (jj < 25) {
        float v = fmaxf(acc + b2[jj], 0.f);
        ac_h2[(size_t)n * 25 + jj] = v;
        atomicAdd(&hg[gids[n] * 49 + jj], v);
    }
}

// ---------------------------------------------------------------------------
// k_g34: hw34 = ac_h2 @ [W3 | W4]   [N,25] -> [N,24]
// ---------------------------------------------------------------------------
__global__ __launch_bounds__(256) void k_g34(const float* __restrict__ ac_h2,
                                             const float* __restrict__ W3,
                                             const float* __restrict__ W4,
                                             float* __restrict__ hw34) {
    __shared__ float xls[128 * 28];
    int tid = threadIdx.x;
    int n0 = blockIdx.x * 128;
    for (int idx = tid; idx < 128 * 28; idx += 256) {
        int r = idx / 28, c = idx - r * 28;
        xls[idx] = (c < 25) ? ac_h2[(size_t)(n0 + r) * 25 + c] : 0.f;
    }
    __syncthreads();
    int j = tid & 31;
    int g = tid >> 5;
    int rbase = g * 16;
    float acc[16];
#pragma unroll
    for (int r = 0; r < 16; ++r) acc[r] = 0.f;
    if (j < 24) {
        for (int i = 0; i < 25; ++i) {
            float w = (j < 13) ? W3[i * 13 + j] : W4[i * 11 + (j - 13)];
#pragma unroll
            for (int rr = 0; rr < 16; ++rr)
                acc[rr] += xls[(rbase + rr) * 28 + i] * w;
        }
#pragma unroll
        for (int rr = 0; rr < 16; ++rr)
            hw34[(size_t)(n0 + rbase + rr) * 24 + j] = acc[rr];
    }
}

// ---------------------------------------------------------------------------
// k_agg34: aggregate hw34 -> ac_h3/ac_h4 (relu+bias), seg-sum into hg[:,25:49]
// ---------------------------------------------------------------------------
__global__ __launch_bounds__(256) void k_agg34(
    const float* __restrict__ hw34, const int* __restrict__ row_ptr,
    const int* __restrict__ s_src, const float* __restrict__ s_w,
    const float* __restrict__ b3, const float* __restrict__ b4,
    const int* __restrict__ gids, float* __restrict__ hg) {
    int tid = threadIdx.x;
    int lane = tid & 63, wave = tid >> 6;
    int half = lane >> 5, jj = lane & 31;
    int n = blockIdx.x * 8 + wave * 2 + half;
    int e0 = row_ptr[n], e1 = row_ptr[n + 1];
    float acc = 0.f;
    for (int e = e0; e < e1; ++e) {
        int s  = s_src[e];
        float w = s_w[e];
        if (jj < 24) acc += w * hw34[(size_t)s * 24 + jj];
    }
    if (jj < 24) {
        float v = (jj < 13) ? fmaxf(acc + b3[jj], 0.f)
                            : fmaxf(acc + b4[jj - 13], 0.f);
        atomicAdd(&hg[gids[n] * 49 + 25 + jj], v);
    }
}

// ---------------------------------------------------------------------------
// k_final: out = (hg @ Wc1 + bc1) @ Wc2 + bc2     [256,49]->[256,5]
// ---------------------------------------------------------------------------
__global__ __launch_bounds__(256) void k_final(
    const float* __restrict__ hg, const float* __restrict__ Wc1,
    const float* __restrict__ bc1, const float* __restrict__ Wc2,
    const float* __restrict__ bc2, float* __restrict__ out) {
    int g = blockIdx.x * blockDim.x + threadIdx.x;
    if (g < N_GRAPHS) {
        float t[27];
#pragma unroll
        for (int j = 0; j < 27; ++j) t[j] = bc1[j];
        for (int i = 0; i < 49; ++i) {
            float hv = hg[g * 49 + i];
#pragma unroll
            for (int j = 0; j < 27; ++j) t[j] += hv * Wc1[i * 27 + j];
        }
#pragma unroll
        for (int j2 = 0; j2 < 5; ++j2) {
            float o = bc2[j2];
#pragma unroll
            for (int i = 0; i < 27; ++i) o += t[i] * Wc2[i * 5 + j2];
            out[g * 5 + j2] = o;
        }
    }
}

// ---------------------------------------------------------------------------
extern "C" void kernel_launch(void* const* d_in, const int* in_sizes, int n_in,
                              void* d_out, int out_size, void* d_ws, size_t ws_size,
                              hipStream_t stream) {
    const float* x    = (const float*)d_in[0];
    const int*   src  = (const int*)d_in[1];
    const int*   dst  = (const int*)d_in[2];
    const int*   gids = (const int*)d_in[3];
    const float* ew   = (const float*)d_in[4];
    const float* w1 = (const float*)d_in[5],  *b1 = (const float*)d_in[6];
    const float* w2 = (const float*)d_in[7],  *b2 = (const float*)d_in[8];
    const float* w3 = (const float*)d_in[9],  *b3 = (const float*)d_in[10];
    const float* W11 = (const float*)d_in[11], *b11 = (const float*)d_in[12];
    const float* W12 = (const float*)d_in[13], *b12 = (const float*)d_in[14];
    const float* W13 = (const float*)d_in[15], *b13 = (const float*)d_in[16];
    const float* W2  = (const float*)d_in[17], *b2g = (const float*)d_in[18];
    const float* W3  = (const float*)d_in[19], *b3g = (const float*)d_in[20];
    const float* W4  = (const float*)d_in[21], *b4g = (const float*)d_in[22];
    const float* Wc1 = (const float*)d_in[23], *bc1 = (const float*)d_in[24];
    const float* Wc2 = (const float*)d_in[25], *bc2 = (const float*)d_in[26];
    float* out = (float*)d_out;

    // workspace layout (256B aligned)
    char* ws = (char*)d_ws;
    size_t off = 0;
    auto alloc = [&](size_t bytes) {
        size_t o = off;
        off = (off + bytes + 255) & ~(size_t)255;
        return (void*)(ws + o);
    };
    int*   cnt     = (int*)alloc(N_NODES * 4);
    int*   row_ptr = (int*)alloc((N_NODES + 1) * 4);
    int*   cursor  = (int*)alloc(N_NODES * 4);
    int*   s_src   = (int*)alloc(N_EDGES * 4);
    float* s_w     = (float*)alloc(N_EDGES * 4);
    float* hw_cat  = (float*)alloc((size_t)N_NODES * 162 * 4);
    float* ac_h1   = (float*)alloc((size_t)N_NODES * 54 * 4);
    float* hg      = (float*)alloc(N_GRAPHS * 49 * 4);
    // later stages alias the (dead) hw_cat region
    float* hw2   = hw_cat;
    float* ac_h2 = hw_cat + (size_t)N_NODES * 25;
    float* hw34  = hw_cat + (size_t)N_NODES * 50;

    k_zero<<<200, 256, 0, stream>>>(hg, cnt);
    k_count<<<N_EDGES / 256, 256, 0, stream>>>(dst, cnt);
    k_scan<<<1, 1024, 0, stream>>>(cnt, row_ptr, cursor);
    k_scatter<<<N_EDGES / 256, 256, 0, stream>>>(src, dst, ew, cursor, s_src, s_w);
    k_conv<<<N_NODES / BN, 256, 0, stream>>>(x, w1, b1, w2, b2, w3, b3,
                                             W11, W12, W13, hw_cat);
    k_agg1<<<N_NODES / 4, 256, 0, stream>>>(hw_cat, row_ptr, s_src, s_w,
                                            b11, b12, b13, ac_h1);
    k_g2<<<N_NODES / 128, 256, 0, stream>>>(ac_h1, W2, hw2);
    k_agg2<<<N_NODES / 8, 256, 0, stream>>>(hw2, row_ptr, s_src, s_w, b2g, gids,
                                            ac_h2, hg);
    k_g34<<<N_NODES / 128, 256, 0, stream>>>(ac_h2, W3, W4, hw34);
    k_agg34<<<N_NODES / 8, 256, 0, stream>>>(hw34, row_ptr, s_src, s_w, b3g, b4g,
                                             gids, hg);
    k_final<<<1, 256, 0, stream>>>(hg, Wc1, bc1, Wc2, bc2, out);
}

// Round 2
// 508.980 us; speedup vs baseline: 2.2196x; 2.2196x over previous
//
#include <hip/hip_runtime.h>
#include <hip/hip_bf16.h>

#define N_NODES 51200
#define N_EDGES 819200
#define N_GRAPHS 256

typedef __attribute__((ext_vector_type(8))) short short8;
typedef __attribute__((ext_vector_type(4))) float f32x4;

__device__ __forceinline__ ushort f2bf(float f) {
    uint u = __builtin_bit_cast(uint, f);
    u += 0x7FFFu + ((u >> 16) & 1u);     // round-to-nearest-even
    return (ushort)(u >> 16);
}
__device__ __forceinline__ float bf2f(ushort h) {
    uint u = ((uint)h) << 16;
    return __builtin_bit_cast(float, u);
}

// ---------------------------------------------------------------------------
// k_zero: zero hg accumulator + dst-degree counters (must re-zero every call)
// ---------------------------------------------------------------------------
__global__ void k_zero(float* __restrict__ hg, int* __restrict__ cnt) {
    int i = blockIdx.x * blockDim.x + threadIdx.x;
    if (i < N_GRAPHS * 49) hg[i] = 0.f;
    if (i < N_NODES) cnt[i] = 0;
}

// ---------------------------------------------------------------------------
// k_pack: bf16-pack conv weights into MFMA B-fragment-friendly layout.
// Wtc[k][s][o][kl]  (3*12*96*32): value = w_k[o][i][t], kk=32s+kl, t=kk>>7, i=kk&127
// Wp1[k][s2][o][kl] (3*3*64*32) : value = W1k[kk2*54+o] (o<54), else 0
// ---------------------------------------------------------------------------
__global__ __launch_bounds__(256) void k_pack(
    const float* __restrict__ w1, const float* __restrict__ w2,
    const float* __restrict__ w3,
    const float* __restrict__ W11, const float* __restrict__ W12,
    const float* __restrict__ W13,
    ushort* __restrict__ Wtc, ushort* __restrict__ Wp1) {
    int idx = blockIdx.x * 256 + threadIdx.x;
    if (idx < 3 * 12 * 96 * 32) {
        int kl = idx & 31;
        int o  = (idx >> 5) % 96;
        int s  = (idx >> 5) / 96 % 12;
        int k  = idx / (32 * 96 * 12);
        int kk = s * 32 + kl;
        int t = kk >> 7, i = kk & 127;
        const float* w = (k == 0) ? w1 : (k == 1) ? w2 : w3;
        Wtc[idx] = f2bf(w[(o * 128 + i) * 3 + t]);
    }
    if (idx < 3 * 3 * 64 * 32) {
        int kl = idx & 31;
        int o  = (idx >> 5) % 64;
        int s2 = (idx >> 5) / 64 % 3;
        int k  = idx / (32 * 64 * 3);
        int kk2 = s2 * 32 + kl;
        const float* W = (k == 0) ? W11 : (k == 1) ? W12 : W13;
        Wp1[idx] = (o < 54) ? f2bf(W[kk2 * 54 + o]) : (ushort)0;
    }
}

// ---------------------------------------------------------------------------
// k_count / k_scan / k_scatter: build dst-CSR
// ---------------------------------------------------------------------------
__global__ void k_count(const int* __restrict__ dst, int* __restrict__ cnt) {
    int e = blockIdx.x * blockDim.x + threadIdx.x;
    if (e < N_EDGES) atomicAdd(&cnt[dst[e]], 1);
}

__global__ __launch_bounds__(1024) void k_scan(const int* __restrict__ cnt,
                                               int* __restrict__ row_ptr,
                                               int* __restrict__ cursor) {
    __shared__ int s[1024];
    int tid = threadIdx.x;
    if (tid == 0) row_ptr[0] = 0;
    int running = 0;
    for (int base = 0; base < N_NODES; base += 1024) {
        int idx = base + tid;
        int v = (idx < N_NODES) ? cnt[idx] : 0;
        s[tid] = v;
        __syncthreads();
        for (int off = 1; off < 1024; off <<= 1) {
            int t = s[tid];
            if (tid >= off) t += s[tid - off];
            __syncthreads();
            s[tid] = t;
            __syncthreads();
        }
        int incl = s[tid];
        int total = s[1023];
        if (idx < N_NODES) {
            row_ptr[idx + 1] = running + incl;
            cursor[idx]      = running + incl - v;
        }
        running += total;
        __syncthreads();
    }
}

__global__ void k_scatter(const int* __restrict__ src, const int* __restrict__ dst,
                          const float* __restrict__ ew,
                          int* __restrict__ cursor,
                          int* __restrict__ s_src, float* __restrict__ s_w) {
    int e = blockIdx.x * blockDim.x + threadIdx.x;
    if (e < N_EDGES) {
        int pos = atomicAdd(&cursor[dst[e]], 1);
        s_src[pos] = src[e];
        s_w[pos]   = ew[e];
    }
}

// ---------------------------------------------------------------------------
// k_conv (MFMA): 3 dilated convs as bf16 GEMMs (K=384 each) + fused
// relu-combine + [96->54] epilogue GEMMs -> hw_cat bf16 [N][176] (162 valid)
// Block = 64 nodes, 4 waves; wave w owns node rows [16w,16w+16), all channels.
// ---------------------------------------------------------------------------
#define BN 64
#define XS_LD 136   // 128 + 8 pad: row stride 272B -> 2-way bank alias (free)
#define HS_LD 104   // 96 + 8 pad

__global__ __launch_bounds__(256) void k_conv(
    const float* __restrict__ x,
    const ushort* __restrict__ Wtc, const ushort* __restrict__ Wp1,
    const float* __restrict__ b1, const float* __restrict__ b2,
    const float* __restrict__ b3,
    ushort* __restrict__ hw_cat) {
    __shared__ ushort xs[70 * XS_LD];        // 19040 B
    __shared__ ushort hsw[4][16 * HS_LD];    // 13312 B

    const int tid = threadIdx.x;
    const int n0  = blockIdx.x * BN;

    // stage x rows [n0-3, n0+67) as bf16, zero-padded ends
    for (int idx = tid; idx < 70 * 32; idx += 256) {
        int row = idx >> 5, c4 = (idx & 31) << 2;
        int node = n0 - 3 + row;
        float4 v = make_float4(0.f, 0.f, 0.f, 0.f);
        if (node >= 0 && node < N_NODES)
            v = *reinterpret_cast<const float4*>(x + (size_t)node * 128 + c4);
        ushort* p = &xs[row * XS_LD + c4];
        p[0] = f2bf(v.x); p[1] = f2bf(v.y); p[2] = f2bf(v.z); p[3] = f2bf(v.w);
    }
    __syncthreads();

    const int lane = tid & 63;
    const int wave = tid >> 6;
    const int r16  = lane & 15;        // A-row / B-col within 16-tile
    const int b8   = (lane >> 4) * 8;  // K sub-block offset

    f32x4 acc[3][6];
#pragma unroll
    for (int k = 0; k < 3; ++k)
#pragma unroll
        for (int ot = 0; ot < 6; ++ot) acc[k][ot] = (f32x4)0.f;

    // conv GEMMs: for conv k (dilation k+1), A[n][kk] = x[n+(t-1)d][i]
    for (int s = 0; s < 12; ++s) {
        const int cbase = (s * 32) & 127;
        const int t     = (s * 32) >> 7;
#pragma unroll
        for (int k = 0; k < 3; ++k) {
            const int roff = (t - 1) * (k + 1) + 3;
            const short8 a = *reinterpret_cast<const short8*>(
                &xs[(wave * 16 + r16 + roff) * XS_LD + cbase + b8]);
            const ushort* wb = Wtc + (((k * 12 + s) * 96 + r16) * 32) + b8;
#pragma unroll
            for (int ot = 0; ot < 6; ++ot) {
                short8 b = *reinterpret_cast<const short8*>(wb + ot * 16 * 32);
                acc[k][ot] = __builtin_amdgcn_mfma_f32_16x16x32_bf16(a, b, acc[k][ot], 0, 0, 0);
            }
        }
    }

    // bias + h01=relu(c1)+c2 ; h02=relu(c2)+c3 ; h03=relu(c3)+c1 (in place)
#pragma unroll
    for (int ot = 0; ot < 6; ++ot) {
        int o = ot * 16 + r16;
        float bb1 = b1[o], bb2 = b2[o], bb3 = b3[o];
#pragma unroll
        for (int r = 0; r < 4; ++r) {
            float C1 = acc[0][ot][r] + bb1;
            float C2 = acc[1][ot][r] + bb2;
            float C3 = acc[2][ot][r] + bb3;
            acc[0][ot][r] = fmaxf(C1, 0.f) + C2;
            acc[1][ot][r] = fmaxf(C2, 0.f) + C3;
            acc[2][ot][r] = fmaxf(C3, 0.f) + C1;
        }
    }

    // epilogue: hw_cat[:, 54k:54k+54] = h0k @ W1k  (MFMA, K=96)
    ushort* hs = hsw[wave];
#pragma unroll
    for (int k = 0; k < 3; ++k) {
        __syncthreads();   // previous k's readers done before overwrite
#pragma unroll
        for (int ot = 0; ot < 6; ++ot)
#pragma unroll
            for (int r = 0; r < 4; ++r)
                hs[((lane >> 4) * 4 + r) * HS_LD + ot * 16 + r16] = f2bf(acc[k][ot][r]);
        __syncthreads();
        f32x4 acc2[4];
#pragma unroll
        for (int ot2 = 0; ot2 < 4; ++ot2) acc2[ot2] = (f32x4)0.f;
#pragma unroll
        for (int s2 = 0; s2 < 3; ++s2) {
            short8 a = *reinterpret_cast<const short8*>(&hs[r16 * HS_LD + s2 * 32 + b8]);
            const ushort* wb = Wp1 + (((k * 3 + s2) * 64 + r16) * 32) + b8;
#pragma unroll
            for (int ot2 = 0; ot2 < 4; ++ot2) {
                short8 b = *reinterpret_cast<const short8*>(wb + ot2 * 16 * 32);
                acc2[ot2] = __builtin_amdgcn_mfma_f32_16x16x32_bf16(a, b, acc2[ot2], 0, 0, 0);
            }
        }
#pragma unroll
        for (int ot2 = 0; ot2 < 4; ++ot2) {
            int co = ot2 * 16 + r16;
            if (co < 54) {
#pragma unroll
                for (int r = 0; r < 4; ++r) {
                    int node = n0 + wave * 16 + (lane >> 4) * 4 + r;
                    hw_cat[(size_t)node * 176 + k * 54 + co] = f2bf(acc2[ot2][r]);
                }
            }
        }
    }
}

// ---------------------------------------------------------------------------
// k_agg1: CSR aggregate of hw_cat (bf16, 3x54) -> ac_h1 = sum_k relu(agg_k+b1k)
// one wave per dst node; lane l<44 owns features 4l..4l+3 (ushort4 loads);
// branch-relu recombined through LDS.
// ---------------------------------------------------------------------------
__global__ __launch_bounds__(256) void k_agg1(
    const ushort* __restrict__ hw, const int* __restrict__ row_ptr,
    const int* __restrict__ s_src, const float* __restrict__ s_w,
    const float* __restrict__ b11, const float* __restrict__ b12,
    const float* __restrict__ b13, float* __restrict__ ac_h1) {
    __shared__ float stage[4][176];
    int tid = threadIdx.x;
    int lane = tid & 63, wave = tid >> 6;
    int n = blockIdx.x * 4 + wave;
    int e0 = row_ptr[n], e1 = row_ptr[n + 1];
    const bool act = lane < 44;
    const int col = lane * 4;
    float a0 = 0.f, a1 = 0.f, a2 = 0.f, a3 = 0.f;
    int e = e0;
    for (; e + 1 < e1; e += 2) {
        int sA = s_src[e], sB = s_src[e + 1];
        float wA = s_w[e], wB = s_w[e + 1];
        if (act) {
            ushort4 vA = *reinterpret_cast<const ushort4*>(hw + (size_t)sA * 176 + col);
            ushort4 vB = *reinterpret_cast<const ushort4*>(hw + (size_t)sB * 176 + col);
            a0 += wA * bf2f(vA.x) + wB * bf2f(vB.x);
            a1 += wA * bf2f(vA.y) + wB * bf2f(vB.y);
            a2 += wA * bf2f(vA.z) + wB * bf2f(vB.z);
            a3 += wA * bf2f(vA.w) + wB * bf2f(vB.w);
        }
    }
    if (e < e1) {
        int sA = s_src[e];
        float wA = s_w[e];
        if (act) {
            ushort4 vA = *reinterpret_cast<const ushort4*>(hw + (size_t)sA * 176 + col);
            a0 += wA * bf2f(vA.x);
            a1 += wA * bf2f(vA.y);
            a2 += wA * bf2f(vA.z);
            a3 += wA * bf2f(vA.w);
        }
    }
    if (act) {
        float av[4] = {a0, a1, a2, a3};
#pragma unroll
        for (int j = 0; j < 4; ++j) {
            int f = col + j;
            float bias = (f < 54) ? b11[f] : (f < 108) ? b12[f - 54]
                        : (f < 162) ? b13[f - 108] : 0.f;
            stage[wave][f] = fmaxf(av[j] + bias, 0.f);
        }
    }
    __syncthreads();
    if (lane < 54)
        ac_h1[(size_t)n * 54 + lane] =
            stage[wave][lane] + stage[wave][lane + 54] + stage[wave][lane + 108];
}

// ---------------------------------------------------------------------------
// k_g2: hw2 = ac_h1 @ W2   [N,54]x[54,25]
// ---------------------------------------------------------------------------
__global__ __launch_bounds__(256) void k_g2(const float* __restrict__ ac_h1,
                                            const float* __restrict__ W2,
                                            float* __restrict__ hw2) {
    __shared__ float xls[128 * 56];
    int tid = threadIdx.x;
    int n0 = blockIdx.x * 128;
    for (int idx = tid; idx < 128 * 56; idx += 256) {
        int r = idx / 56, c = idx - r * 56;
        xls[idx] = (c < 54) ? ac_h1[(size_t)(n0 + r) * 54 + c] : 0.f;
    }
    __syncthreads();
    int j = tid & 31;
    int g = tid >> 5;
    int rbase = g * 16;
    float acc[16];
#pragma unroll
    for (int r = 0; r < 16; ++r) acc[r] = 0.f;
    if (j < 25) {
        for (int i = 0; i < 54; ++i) {
            float w = W2[i * 25 + j];
#pragma unroll
            for (int rr = 0; rr < 16; ++rr)
                acc[rr] += xls[(rbase + rr) * 56 + i] * w;
        }
#pragma unroll
        for (int rr = 0; rr < 16; ++rr)
            hw2[(size_t)(n0 + rbase + rr) * 25 + j] = acc[rr];
    }
}

// ---------------------------------------------------------------------------
// k_agg2: aggregate hw2 -> ac_h2 = relu(agg + b2); seg-sum into hg[:,0:25]
// ---------------------------------------------------------------------------
__global__ __launch_bounds__(256) void k_agg2(
    const float* __restrict__ hw2, const int* __restrict__ row_ptr,
    const int* __restrict__ s_src, const float* __restrict__ s_w,
    const float* __restrict__ b2, const int* __restrict__ gids,
    float* __restrict__ ac_h2, float* __restrict__ hg) {
    int tid = threadIdx.x;
    int lane = tid & 63, wave = tid >> 6;
    int half = lane >> 5, jj = lane & 31;
    int n = blockIdx.x * 8 + wave * 2 + half;
    int e0 = row_ptr[n], e1 = row_ptr[n + 1];
    float acc = 0.f;
    for (int e = e0; e < e1; ++e) {
        int s  = s_src[e];
        float w = s_w[e];
        if (jj < 25) acc += w * hw2[(size_t)s * 25 + jj];
    }
    if (jj < 25) {
        float v = fmaxf(acc + b2[jj], 0.f);
        ac_h2[(size_t)n * 25 + jj] = v;
        atomicAdd(&hg[gids[n] * 49 + jj], v);
    }
}

// ---------------------------------------------------------------------------
// k_g34: hw34 = ac_h2 @ [W3 | W4]   [N,25] -> [N,24]
// ---------------------------------------------------------------------------
__global__ __launch_bounds__(256) void k_g34(const float* __restrict__ ac_h2,
                                             const float* __restrict__ W3,
                                             const float* __restrict__ W4,
                                             float* __restrict__ hw34) {
    __shared__ float xls[128 * 28];
    int tid = threadIdx.x;
    int n0 = blockIdx.x * 128;
    for (int idx = tid; idx < 128 * 28; idx += 256) {
        int r = idx / 28, c = idx - r * 28;
        xls[idx] = (c < 25) ? ac_h2[(size_t)(n0 + r) * 25 + c] : 0.f;
    }
    __syncthreads();
    int j = tid & 31;
    int g = tid >> 5;
    int rbase = g * 16;
    float acc[16];
#pragma unroll
    for (int r = 0; r < 16; ++r) acc[r] = 0.f;
    if (j < 24) {
        for (int i = 0; i < 25; ++i) {
            float w = (j < 13) ? W3[i * 13 + j] : W4[i * 11 + (j - 13)];
#pragma unroll
            for (int rr = 0; rr < 16; ++rr)
                acc[rr] += xls[(rbase + rr) * 28 + i] * w;
        }
#pragma unroll
        for (int rr = 0; rr < 16; ++rr)
            hw34[(size_t)(n0 + rbase + rr) * 24 + j] = acc[rr];
    }
}

// ---------------------------------------------------------------------------
// k_agg34: aggregate hw34 -> relu+bias, seg-sum into hg[:,25:49]
// ---------------------------------------------------------------------------
__global__ __launch_bounds__(256) void k_agg34(
    const float* __restrict__ hw34, const int* __restrict__ row_ptr,
    const int* __restrict__ s_src, const float* __restrict__ s_w,
    const float* __restrict__ b3, const float* __restrict__ b4,
    const int* __restrict__ gids, float* __restrict__ hg) {
    int tid = threadIdx.x;
    int lane = tid & 63, wave = tid >> 6;
    int half = lane >> 5, jj = lane & 31;
    int n = blockIdx.x * 8 + wave * 2 + half;
    int e0 = row_ptr[n], e1 = row_ptr[n + 1];
    float acc = 0.f;
    for (int e = e0; e < e1; ++e) {
        int s  = s_src[e];
        float w = s_w[e];
        if (jj < 24) acc += w * hw34[(size_t)s * 24 + jj];
    }
    if (jj < 24) {
        float v = (jj < 13) ? fmaxf(acc + b3[jj], 0.f)
                            : fmaxf(acc + b4[jj - 13], 0.f);
        atomicAdd(&hg[gids[n] * 49 + 25 + jj], v);
    }
}

// ---------------------------------------------------------------------------
// k_final: out = (hg @ Wc1 + bc1) @ Wc2 + bc2     [256,49]->[256,5]
// ---------------------------------------------------------------------------
__global__ __launch_bounds__(256) void k_final(
    const float* __restrict__ hg, const float* __restrict__ Wc1,
    const float* __restrict__ bc1, const float* __restrict__ Wc2,
    const float* __restrict__ bc2, float* __restrict__ out) {
    int g = blockIdx.x * blockDim.x + threadIdx.x;
    if (g < N_GRAPHS) {
        float t[27];
#pragma unroll
        for (int j = 0; j < 27; ++j) t[j] = bc1[j];
        for (int i = 0; i < 49; ++i) {
            float hv = hg[g * 49 + i];
#pragma unroll
            for (int j = 0; j < 27; ++j) t[j] += hv * Wc1[i * 27 + j];
        }
#pragma unroll
        for (int j2 = 0; j2 < 5; ++j2) {
            float o = bc2[j2];
#pragma unroll
            for (int i = 0; i < 27; ++i) o += t[i] * Wc2[i * 5 + j2];
            out[g * 5 + j2] = o;
        }
    }
}

// ---------------------------------------------------------------------------
extern "C" void kernel_launch(void* const* d_in, const int* in_sizes, int n_in,
                              void* d_out, int out_size, void* d_ws, size_t ws_size,
                              hipStream_t stream) {
    const float* x    = (const float*)d_in[0];
    const int*   src  = (const int*)d_in[1];
    const int*   dst  = (const int*)d_in[2];
    const int*   gids = (const int*)d_in[3];
    const float* ew   = (const float*)d_in[4];
    const float* w1 = (const float*)d_in[5],  *b1 = (const float*)d_in[6];
    const float* w2 = (const float*)d_in[7],  *b2 = (const float*)d_in[8];
    const float* w3 = (const float*)d_in[9],  *b3 = (const float*)d_in[10];
    const float* W11 = (const float*)d_in[11], *b11 = (const float*)d_in[12];
    const float* W12 = (const float*)d_in[13], *b12 = (const float*)d_in[14];
    const float* W13 = (const float*)d_in[15], *b13 = (const float*)d_in[16];
    const float* W2  = (const float*)d_in[17], *b2g = (const float*)d_in[18];
    const float* W3  = (const float*)d_in[19], *b3g = (const float*)d_in[20];
    const float* W4  = (const float*)d_in[21], *b4g = (const float*)d_in[22];
    const float* Wc1 = (const float*)d_in[23], *bc1 = (const float*)d_in[24];
    const float* Wc2 = (const float*)d_in[25], *bc2 = (const float*)d_in[26];
    float* out = (float*)d_out;

    char* ws = (char*)d_ws;
    size_t off = 0;
    auto alloc = [&](size_t bytes) {
        size_t o = off;
        off = (off + bytes + 255) & ~(size_t)255;
        return (void*)(ws + o);
    };
    int*    cnt     = (int*)alloc(N_NODES * 4);
    int*    row_ptr = (int*)alloc((N_NODES + 1) * 4);
    int*    cursor  = (int*)alloc(N_NODES * 4);
    int*    s_src   = (int*)alloc(N_EDGES * 4);
    float*  s_w     = (float*)alloc(N_EDGES * 4);
    ushort* hw_cat  = (ushort*)alloc((size_t)N_NODES * 176 * 2);  // bf16
    float*  ac_h1   = (float*)alloc((size_t)N_NODES * 54 * 4);
    float*  hg      = (float*)alloc(N_GRAPHS * 49 * 4);
    ushort* Wtc     = (ushort*)alloc(3 * 12 * 96 * 32 * 2);
    ushort* Wp1     = (ushort*)alloc(3 * 3 * 64 * 32 * 2);
    float*  hw2     = (float*)alloc((size_t)N_NODES * 25 * 4);
    // aliases of dead regions:
    float*  ac_h2   = ac_h1;         // ac_h1 dead after k_g2
    float*  hw34    = hw2;           // hw2 dead after k_agg2

    k_zero<<<200, 256, 0, stream>>>(hg, cnt);
    k_pack<<<(3 * 12 * 96 * 32 + 255) / 256, 256, 0, stream>>>(
        w1, w2, w3, W11, W12, W13, Wtc, Wp1);
    k_count<<<N_EDGES / 256, 256, 0, stream>>>(dst, cnt);
    k_scan<<<1, 1024, 0, stream>>>(cnt, row_ptr, cursor);
    k_scatter<<<N_EDGES / 256, 256, 0, stream>>>(src, dst, ew, cursor, s_src, s_w);
    k_conv<<<N_NODES / BN, 256, 0, stream>>>(x, Wtc, Wp1, b1, b2, b3, hw_cat);
    k_agg1<<<N_NODES / 4, 256, 0, stream>>>(hw_cat, row_ptr, s_src, s_w,
                                            b11, b12, b13, ac_h1);
    k_g2<<<N_NODES / 128, 256, 0, stream>>>(ac_h1, W2, hw2);
    k_agg2<<<N_NODES / 8, 256, 0, stream>>>(hw2, row_ptr, s_src, s_w, b2g, gids,
                                            ac_h2, hg);
    k_g34<<<N_NODES / 128, 256, 0, stream>>>(ac_h2, W3, W4, hw34);
    k_agg34<<<N_NODES / 8, 256, 0, stream>>>(hw34, row_ptr, s_src, s_w, b3g, b4g,
                                             gids, hg);
    k_final<<<1, 256, 0, stream>>>(hg, Wc1, bc1, Wc2, bc2, out);
}

// Round 3
// 362.879 us; speedup vs baseline: 3.1133x; 1.4026x over previous
//
#include <hip/hip_runtime.h>
#include <hip/hip_bf16.h>

#define N_NODES 51200
#define N_EDGES 819200
#define N_GRAPHS 256

typedef __attribute__((ext_vector_type(8))) short short8;
typedef __attribute__((ext_vector_type(4))) float f32x4;

__device__ __forceinline__ ushort f2bf(float f) {
    uint u = __builtin_bit_cast(uint, f);
    u += 0x7FFFu + ((u >> 16) & 1u);     // round-to-nearest-even
    return (ushort)(u >> 16);
}
__device__ __forceinline__ float bf2f(ushort h) {
    uint u = ((uint)h) << 16;
    return __builtin_bit_cast(float, u);
}

// ---------------------------------------------------------------------------
// k_init: zero hg + cnt, and bf16-pack conv weights into MFMA B layouts.
// Wtc[k][s][o][kl]  (3*12*96*32): w_k[o][i][t], kk=32s+kl, t=kk>>7, i=kk&127
// Wp1[k][s2][o][kl] (3*3*64*32) : W1k[kk2*54+o] (o<54), else 0
// ---------------------------------------------------------------------------
__global__ __launch_bounds__(256) void k_init(
    const float* __restrict__ w1, const float* __restrict__ w2,
    const float* __restrict__ w3,
    const float* __restrict__ W11, const float* __restrict__ W12,
    const float* __restrict__ W13,
    ushort* __restrict__ Wtc, ushort* __restrict__ Wp1,
    float* __restrict__ hg, int* __restrict__ cnt) {
    int idx = blockIdx.x * 256 + threadIdx.x;
    if (idx < N_GRAPHS * 49) hg[idx] = 0.f;
    if (idx < N_NODES) cnt[idx] = 0;
    if (idx < 3 * 12 * 96 * 32) {
        int kl = idx & 31;
        int o  = (idx >> 5) % 96;
        int s  = (idx >> 5) / 96 % 12;
        int k  = idx / (32 * 96 * 12);
        int kk = s * 32 + kl;
        int t = kk >> 7, i = kk & 127;
        const float* w = (k == 0) ? w1 : (k == 1) ? w2 : w3;
        Wtc[idx] = f2bf(w[(o * 128 + i) * 3 + t]);
    }
    if (idx < 3 * 3 * 64 * 32) {
        int kl = idx & 31;
        int o  = (idx >> 5) % 64;
        int s2 = (idx >> 5) / 64 % 3;
        int k  = idx / (32 * 64 * 3);
        int kk2 = s2 * 32 + kl;
        const float* W = (k == 0) ? W11 : (k == 1) ? W12 : W13;
        Wp1[idx] = (o < 54) ? f2bf(W[kk2 * 54 + o]) : (ushort)0;
    }
}

// ---------------------------------------------------------------------------
// CSR build: count -> multi-block scan -> scatter
// ---------------------------------------------------------------------------
__global__ void k_count(const int* __restrict__ dst, int* __restrict__ cnt) {
    int e = blockIdx.x * blockDim.x + threadIdx.x;
    if (e < N_EDGES) atomicAdd(&cnt[dst[e]], 1);
}

// 50 blocks x 1024: local inclusive scan; cursor[i] holds local inclusive sum
__global__ __launch_bounds__(1024) void k_scan1(const int* __restrict__ cnt,
                                                int* __restrict__ cursor,
                                                int* __restrict__ bsum) {
    __shared__ int s[1024];
    int tid = threadIdx.x;
    int idx = blockIdx.x * 1024 + tid;      // 51200 = 50*1024 exactly
    int v = cnt[idx];
    s[tid] = v;
    __syncthreads();
    for (int off = 1; off < 1024; off <<= 1) {
        int t = s[tid];
        if (tid >= off) t += s[tid - off];
        __syncthreads();
        s[tid] = t;
        __syncthreads();
    }
    cursor[idx] = s[tid];
    if (tid == 1023) bsum[blockIdx.x] = s[1023];
}

__global__ void k_scan2(const int* __restrict__ bsum, int* __restrict__ boff) {
    if (threadIdx.x == 0 && blockIdx.x == 0) {
        int r = 0;
        for (int b = 0; b < 50; ++b) { boff[b] = r; r += bsum[b]; }
    }
}

__global__ __launch_bounds__(256) void k_scan3(const int* __restrict__ cnt,
                                               const int* __restrict__ boff,
                                               int* __restrict__ row_ptr,
                                               int* __restrict__ cursor) {
    int i = blockIdx.x * 256 + threadIdx.x;
    if (i < N_NODES) {
        int incl = cursor[i] + boff[i >> 10];
        row_ptr[i + 1] = incl;
        cursor[i] = incl - cnt[i];          // exclusive = row start
    }
    if (i == 0) row_ptr[0] = 0;
}

__global__ void k_scatter(const int* __restrict__ src, const int* __restrict__ dst,
                          const float* __restrict__ ew,
                          int* __restrict__ cursor,
                          int* __restrict__ s_src, float* __restrict__ s_w) {
    int e = blockIdx.x * blockDim.x + threadIdx.x;
    if (e < N_EDGES) {
        int pos = atomicAdd(&cursor[dst[e]], 1);
        s_src[pos] = src[e];
        s_w[pos]   = ew[e];
    }
}

// ---------------------------------------------------------------------------
// k_conv: 3 dilated convs as bf16 MFMA GEMMs with LDS-staged weights
// (register-prefetch pipeline), fused relu-combine + [96->54] epilogue,
// LDS row staging -> contiguous 16B stores of hw_cat bf16 [N][176].
// ---------------------------------------------------------------------------
#define BN 64
#define XS_LD 136
#define HS_LD 104

__global__ __launch_bounds__(256, 1) void k_conv(
    const float* __restrict__ x,
    const ushort* __restrict__ Wtc, const ushort* __restrict__ Wp1g,
    const float* __restrict__ b1, const float* __restrict__ b2,
    const float* __restrict__ b3,
    ushort* __restrict__ hw_cat) {
    __shared__ ushort xs[70 * XS_LD];     // 19040 B
    __shared__ ushort wl[36864];          // 73728 B: one conv's weights [12][96][32]
    // epilogue aliases of wl (all uses strictly after conv loop):
    ushort* wp   = wl;                    // [3][3][64][32] = 18432 ushorts
    ushort* hrow = wl + 18432;            // [64][176]      = 11264 ushorts
    ushort* hswb = wl + 29696;            // [4][16*HS_LD]  =  6656 ushorts

    const int tid = threadIdx.x;
    const int n0  = blockIdx.x * BN;

    // stage x rows [n0-3, n0+67) as bf16, zero-padded ends
    for (int idx = tid; idx < 70 * 32; idx += 256) {
        int row = idx >> 5, c4 = (idx & 31) << 2;
        int node = n0 - 3 + row;
        float4 v = make_float4(0.f, 0.f, 0.f, 0.f);
        if (node >= 0 && node < N_NODES)
            v = *reinterpret_cast<const float4*>(x + (size_t)node * 128 + c4);
        ushort* p = &xs[row * XS_LD + c4];
        p[0] = f2bf(v.x); p[1] = f2bf(v.y); p[2] = f2bf(v.z); p[3] = f2bf(v.w);
    }

    const int lane = tid & 63;
    const int wave = tid >> 6;
    const int r16  = lane & 15;
    const int b8   = (lane >> 4) * 8;

    f32x4 acc[3][6];
#pragma unroll
    for (int k = 0; k < 3; ++k)
#pragma unroll
        for (int ot = 0; ot < 6; ++ot) acc[k][ot] = (f32x4)0.f;

    // prefetch conv0 weights into registers (18 x 16B per thread)
    short8 wreg[18];
    short8 wpreg[9];
#pragma unroll
    for (int i = 0; i < 18; ++i)
        wreg[i] = *reinterpret_cast<const short8*>(Wtc + (size_t)(i * 256 + tid) * 8);

#pragma unroll
    for (int k = 0; k < 3; ++k) {
        __syncthreads();   // (k=0: xs ready) / prior conv's wl readers done
#pragma unroll
        for (int i = 0; i < 18; ++i)
            *reinterpret_cast<short8*>(wl + (i * 256 + tid) * 8) = wreg[i];
        __syncthreads();
        if (k < 2) {       // prefetch next conv's weights under this conv's MFMAs
            const ushort* nw = Wtc + (size_t)(k + 1) * 36864;
#pragma unroll
            for (int i = 0; i < 18; ++i)
                wreg[i] = *reinterpret_cast<const short8*>(nw + (size_t)(i * 256 + tid) * 8);
        } else {           // prefetch epilogue weights
#pragma unroll
            for (int i = 0; i < 9; ++i)
                wpreg[i] = *reinterpret_cast<const short8*>(Wp1g + (size_t)(i * 256 + tid) * 8);
        }
        const int dk = k + 1;
#pragma unroll
        for (int s = 0; s < 12; ++s) {
            const int cbase = (s * 32) & 127;
            const int t     = (s * 32) >> 7;
            const int roff  = (t - 1) * dk + 3;
            short8 a = *reinterpret_cast<const short8*>(
                &xs[(wave * 16 + r16 + roff) * XS_LD + cbase + b8]);
#pragma unroll
            for (int ot = 0; ot < 6; ++ot) {
                short8 b = *reinterpret_cast<const short8*>(
                    &wl[(s * 96 + ot * 16 + r16) * 32 + b8]);
                acc[k][ot] = __builtin_amdgcn_mfma_f32_16x16x32_bf16(a, b, acc[k][ot], 0, 0, 0);
            }
        }
    }

    // bias + branch combine (in place)
#pragma unroll
    for (int ot = 0; ot < 6; ++ot) {
        int o = ot * 16 + r16;
        float bb1 = b1[o], bb2 = b2[o], bb3 = b3[o];
#pragma unroll
        for (int r = 0; r < 4; ++r) {
            float C1 = acc[0][ot][r] + bb1;
            float C2 = acc[1][ot][r] + bb2;
            float C3 = acc[2][ot][r] + bb3;
            acc[0][ot][r] = fmaxf(C1, 0.f) + C2;
            acc[1][ot][r] = fmaxf(C2, 0.f) + C3;
            acc[2][ot][r] = fmaxf(C3, 0.f) + C1;
        }
    }

    // stage epilogue weights into LDS (wl region now dead for conv reads)
    __syncthreads();
#pragma unroll
    for (int i = 0; i < 9; ++i)
        *reinterpret_cast<short8*>(wp + (i * 256 + tid) * 8) = wpreg[i];
    __syncthreads();

    // epilogue: hrow[:, 54k:54k+54] = h0k @ W1k  (MFMA, K=96)
    ushort* hs = hswb + wave * (16 * HS_LD);
#pragma unroll
    for (int k = 0; k < 3; ++k) {
        __syncthreads();
#pragma unroll
        for (int ot = 0; ot < 6; ++ot)
#pragma unroll
            for (int r = 0; r < 4; ++r)
                hs[((lane >> 4) * 4 + r) * HS_LD + ot * 16 + r16] = f2bf(acc[k][ot][r]);
        __syncthreads();
        f32x4 acc2[4];
#pragma unroll
        for (int ot2 = 0; ot2 < 4; ++ot2) acc2[ot2] = (f32x4)0.f;
#pragma unroll
        for (int s2 = 0; s2 < 3; ++s2) {
            short8 a = *reinterpret_cast<const short8*>(&hs[r16 * HS_LD + s2 * 32 + b8]);
#pragma unroll
            for (int ot2 = 0; ot2 < 4; ++ot2) {
                short8 b = *reinterpret_cast<const short8*>(
                    &wp[((k * 3 + s2) * 64 + ot2 * 16 + r16) * 32 + b8]);
                acc2[ot2] = __builtin_amdgcn_mfma_f32_16x16x32_bf16(a, b, acc2[ot2], 0, 0, 0);
            }
        }
#pragma unroll
        for (int ot2 = 0; ot2 < 4; ++ot2) {
            int co = ot2 * 16 + r16;
            if (co < 54) {
#pragma unroll
                for (int r = 0; r < 4; ++r) {
                    int rloc = wave * 16 + (lane >> 4) * 4 + r;
                    hrow[rloc * 176 + k * 54 + co] = f2bf(acc2[ot2][r]);
                }
            }
        }
    }
    // zero pad cols 162..175
    for (int idx = tid; idx < 64 * 14; idx += 256) {
        int r = idx / 14, c = 162 + (idx - r * 14);
        hrow[r * 176 + c] = 0;
    }
    __syncthreads();
    // contiguous copy-out: 64*176 ushorts = 1408 x 16B
    {
        ushort* gdst = hw_cat + (size_t)n0 * 176;
        for (int i = tid; i < 1408; i += 256)
            *reinterpret_cast<short8*>(gdst + i * 8) =
                *reinterpret_cast<const short8*>(hrow + i * 8);
    }
}

// ---------------------------------------------------------------------------
// k_agg1: CSR aggregate of hw_cat (bf16, 3x54) -> ac_h1 = sum relu(agg+b),
// fused with hw2 = ac_h1 @ W2 -> bf16 [N][28]. One wave per dst node.
// ---------------------------------------------------------------------------
__global__ __launch_bounds__(256) void k_agg1(
    const ushort* __restrict__ hw, const int* __restrict__ row_ptr,
    const int* __restrict__ s_src, const float* __restrict__ s_w,
    const float* __restrict__ b11, const float* __restrict__ b12,
    const float* __restrict__ b13, const float* __restrict__ W2,
    ushort* __restrict__ hw2) {
    __shared__ float stage[4][176];
    __shared__ float w2s[54 * 25];
    int tid = threadIdx.x;
    for (int i = tid; i < 54 * 25; i += 256) w2s[i] = W2[i];
    int lane = tid & 63, wave = tid >> 6;
    int n = blockIdx.x * 4 + wave;
    int e0 = row_ptr[n], e1 = row_ptr[n + 1];
    const bool act = lane < 44;
    const int col = lane * 4;
    float a0 = 0.f, a1 = 0.f, a2 = 0.f, a3 = 0.f;
    int e = e0;
    for (; e + 1 < e1; e += 2) {
        int sA = s_src[e], sB = s_src[e + 1];
        float wA = s_w[e], wB = s_w[e + 1];
        if (act) {
            ushort4 vA = *reinterpret_cast<const ushort4*>(hw + (size_t)sA * 176 + col);
            ushort4 vB = *reinterpret_cast<const ushort4*>(hw + (size_t)sB * 176 + col);
            a0 += wA * bf2f(vA.x) + wB * bf2f(vB.x);
            a1 += wA * bf2f(vA.y) + wB * bf2f(vB.y);
            a2 += wA * bf2f(vA.z) + wB * bf2f(vB.z);
            a3 += wA * bf2f(vA.w) + wB * bf2f(vB.w);
        }
    }
    if (e < e1) {
        int sA = s_src[e];
        float wA = s_w[e];
        if (act) {
            ushort4 vA = *reinterpret_cast<const ushort4*>(hw + (size_t)sA * 176 + col);
            a0 += wA * bf2f(vA.x);
            a1 += wA * bf2f(vA.y);
            a2 += wA * bf2f(vA.z);
            a3 += wA * bf2f(vA.w);
        }
    }
    if (act) {
        float av[4] = {a0, a1, a2, a3};
#pragma unroll
        for (int j = 0; j < 4; ++j) {
            int f = col + j;
            float bias = (f < 54) ? b11[f] : (f < 108) ? b12[f - 54]
                        : (f < 162) ? b13[f - 108] : 0.f;
            stage[wave][f] = fmaxf(av[j] + bias, 0.f);
        }
    }
    __syncthreads();          // stage + w2s ready
    if (lane < 54)
        stage[wave][lane] = stage[wave][lane] + stage[wave][lane + 54] +
                            stage[wave][lane + 108];
    __syncthreads();
    // GEMV: hw2[n][j] = sum_i ac1[i] * W2[i][j]
    if (lane < 25) {
        float acc = 0.f;
#pragma unroll
        for (int i = 0; i < 54; ++i) acc += stage[wave][i] * w2s[i * 25 + lane];
        hw2[(size_t)n * 28 + lane] = f2bf(acc);
    }
}

// ---------------------------------------------------------------------------
// k_agg2: aggregate hw2 (bf16) -> ac_h2 = relu(agg+b2); seg-sum into hg[:,0:25];
// fused hw34 = ac_h2 @ [W3|W4] -> bf16 [N][24]. Two nodes per wave.
// ---------------------------------------------------------------------------
__global__ __launch_bounds__(256) void k_agg2(
    const ushort* __restrict__ hw2, const int* __restrict__ row_ptr,
    const int* __restrict__ s_src, const float* __restrict__ s_w,
    const float* __restrict__ b2, const float* __restrict__ W3,
    const float* __restrict__ W4, const int* __restrict__ gids,
    ushort* __restrict__ hw34, float* __restrict__ hg) {
    __shared__ float w34s[25 * 24];
    __shared__ float vst[8][26];
    int tid = threadIdx.x;
    for (int i = tid; i < 25 * 24; i += 256) {
        int ii = i / 24, j = i - ii * 24;
        w34s[i] = (j < 13) ? W3[ii * 13 + j] : W4[ii * 11 + (j - 13)];
    }
    int lane = tid & 63, wave = tid >> 6;
    int half = lane >> 5, jj = lane & 31;
    int n0b = blockIdx.x * 8;
    int n = n0b + wave * 2 + half;
    int e0 = row_ptr[n], e1 = row_ptr[n + 1];
    float acc = 0.f;
    int e = e0;
    for (; e + 1 < e1; e += 2) {
        int sA = s_src[e], sB = s_src[e + 1];
        float wA = s_w[e], wB = s_w[e + 1];
        if (jj < 25)
            acc += wA * bf2f(hw2[(size_t)sA * 28 + jj]) +
                   wB * bf2f(hw2[(size_t)sB * 28 + jj]);
    }
    if (e < e1) {
        if (jj < 25) acc += s_w[e] * bf2f(hw2[(size_t)s_src[e] * 28 + jj]);
    }
    if (jj < 25) {
        float v = fmaxf(acc + b2[jj], 0.f);
        vst[wave * 2 + half][jj] = v;
        atomicAdd(&hg[gids[n] * 49 + jj], v);
    }
    __syncthreads();
    if (tid < 192) {
        int node = tid / 24, j = tid - node * 24;
        float a = 0.f;
#pragma unroll
        for (int i = 0; i < 25; ++i) a += vst[node][i] * w34s[i * 24 + j];
        hw34[(size_t)(n0b + node) * 24 + j] = f2bf(a);
    }
}

// ---------------------------------------------------------------------------
// k_agg34: aggregate hw34 (bf16) -> relu+bias, seg-sum into hg[:,25:49]
// ---------------------------------------------------------------------------
__global__ __launch_bounds__(256) void k_agg34(
    const ushort* __restrict__ hw34, const int* __restrict__ row_ptr,
    const int* __restrict__ s_src, const float* __restrict__ s_w,
    const float* __restrict__ b3, const float* __restrict__ b4,
    const int* __restrict__ gids, float* __restrict__ hg) {
    int tid = threadIdx.x;
    int lane = tid & 63, wave = tid >> 6;
    int half = lane >> 5, jj = lane & 31;
    int n = blockIdx.x * 8 + wave * 2 + half;
    int e0 = row_ptr[n], e1 = row_ptr[n + 1];
    float acc = 0.f;
    int e = e0;
    for (; e + 1 < e1; e += 2) {
        int sA = s_src[e], sB = s_src[e + 1];
        float wA = s_w[e], wB = s_w[e + 1];
        if (jj < 24)
            acc += wA * bf2f(hw34[(size_t)sA * 24 + jj]) +
                   wB * bf2f(hw34[(size_t)sB * 24 + jj]);
    }
    if (e < e1) {
        if (jj < 24) acc += s_w[e] * bf2f(hw34[(size_t)s_src[e] * 24 + jj]);
    }
    if (jj < 24) {
        float v = (jj < 13) ? fmaxf(acc + b3[jj], 0.f)
                            : fmaxf(acc + b4[jj - 13], 0.f);
        atomicAdd(&hg[gids[n] * 49 + 25 + jj], v);
    }
}

// ---------------------------------------------------------------------------
// k_final: out = (hg @ Wc1 + bc1) @ Wc2 + bc2     [256,49]->[256,5]
// ---------------------------------------------------------------------------
__global__ __launch_bounds__(256) void k_final(
    const float* __restrict__ hg, const float* __restrict__ Wc1,
    const float* __restrict__ bc1, const float* __restrict__ Wc2,
    const float* __restrict__ bc2, float* __restrict__ out) {
    int g = blockIdx.x * blockDim.x + threadIdx.x;
    if (g < N_GRAPHS) {
        float t[27];
#pragma unroll
        for (int j = 0; j < 27; ++j) t[j] = bc1[j];
        for (int i = 0; i < 49; ++i) {
            float hv = hg[g * 49 + i];
#pragma unroll
            for (int j = 0; j < 27; ++j) t[j] += hv * Wc1[i * 27 + j];
        }
#pragma unroll
        for (int j2 = 0; j2 < 5; ++j2) {
            float o = bc2[j2];
#pragma unroll
            for (int i = 0; i < 27; ++i) o += t[i] * Wc2[i * 5 + j2];
            out[g * 5 + j2] = o;
        }
    }
}

// ---------------------------------------------------------------------------
extern "C" void kernel_launch(void* const* d_in, const int* in_sizes, int n_in,
                              void* d_out, int out_size, void* d_ws, size_t ws_size,
                              hipStream_t stream) {
    const float* x    = (const float*)d_in[0];
    const int*   src  = (const int*)d_in[1];
    const int*   dst  = (const int*)d_in[2];
    const int*   gids = (const int*)d_in[3];
    const float* ew   = (const float*)d_in[4];
    const float* w1 = (const float*)d_in[5],  *b1 = (const float*)d_in[6];
    const float* w2 = (const float*)d_in[7],  *b2 = (const float*)d_in[8];
    const float* w3 = (const float*)d_in[9],  *b3 = (const float*)d_in[10];
    const float* W11 = (const float*)d_in[11], *b11 = (const float*)d_in[12];
    const float* W12 = (const float*)d_in[13], *b12 = (const float*)d_in[14];
    const float* W13 = (const float*)d_in[15], *b13 = (const float*)d_in[16];
    const float* W2  = (const float*)d_in[17], *b2g = (const float*)d_in[18];
    const float* W3  = (const float*)d_in[19], *b3g = (const float*)d_in[20];
    const float* W4  = (const float*)d_in[21], *b4g = (const float*)d_in[22];
    const float* Wc1 = (const float*)d_in[23], *bc1 = (const float*)d_in[24];
    const float* Wc2 = (const float*)d_in[25], *bc2 = (const float*)d_in[26];
    float* out = (float*)d_out;

    char* ws = (char*)d_ws;
    size_t off = 0;
    auto alloc = [&](size_t bytes) {
        size_t o = off;
        off = (off + bytes + 255) & ~(size_t)255;
        return (void*)(ws + o);
    };
    int*    cnt     = (int*)alloc(N_NODES * 4);
    int*    row_ptr = (int*)alloc((N_NODES + 1) * 4);
    int*    cursor  = (int*)alloc(N_NODES * 4);
    int*    bsum    = (int*)alloc(64 * 4);
    int*    boff    = (int*)alloc(64 * 4);
    int*    s_src   = (int*)alloc(N_EDGES * 4);
    float*  s_w     = (float*)alloc(N_EDGES * 4);
    ushort* hw_cat  = (ushort*)alloc((size_t)N_NODES * 176 * 2);
    ushort* hw2     = (ushort*)alloc((size_t)N_NODES * 28 * 2);
    ushort* hw34    = (ushort*)alloc((size_t)N_NODES * 24 * 2);
    float*  hg      = (float*)alloc(N_GRAPHS * 49 * 4);
    ushort* Wtc     = (ushort*)alloc(3 * 12 * 96 * 32 * 2);
    ushort* Wp1     = (ushort*)alloc(3 * 3 * 64 * 32 * 2);

    k_init<<<(3 * 12 * 96 * 32 + 255) / 256, 256, 0, stream>>>(
        w1, w2, w3, W11, W12, W13, Wtc, Wp1, hg, cnt);
    k_count<<<N_EDGES / 256, 256, 0, stream>>>(dst, cnt);
    k_scan1<<<50, 1024, 0, stream>>>(cnt, cursor, bsum);
    k_scan2<<<1, 64, 0, stream>>>(bsum, boff);
    k_scan3<<<200, 256, 0, stream>>>(cnt, boff, row_ptr, cursor);
    k_scatter<<<N_EDGES / 256, 256, 0, stream>>>(src, dst, ew, cursor, s_src, s_w);
    k_conv<<<N_NODES / BN, 256, 0, stream>>>(x, Wtc, Wp1, b1, b2, b3, hw_cat);
    k_agg1<<<N_NODES / 4, 256, 0, stream>>>(hw_cat, row_ptr, s_src, s_w,
                                            b11, b12, b13, W2, hw2);
    k_agg2<<<N_NODES / 8, 256, 0, stream>>>(hw2, row_ptr, s_src, s_w, b2g,
                                            W3, W4, gids, hw34, hg);
    k_agg34<<<N_NODES / 8, 256, 0, stream>>>(hw34, row_ptr, s_src, s_w, b3g, b4g,
                                             gids, hg);
    k_final<<<1, 256, 0, stream>>>(hg, Wc1, bc1, Wc2, bc2, out);
}

// Round 4
// 291.892 us; speedup vs baseline: 3.8705x; 1.2432x over previous
//
#include <hip/hip_runtime.h>
#include <hip/hip_bf16.h>

#define N_NODES 51200
#define N_EDGES 819200
#define N_GRAPHS 256

typedef __attribute__((ext_vector_type(8))) short short8;
typedef __attribute__((ext_vector_type(4))) float f32x4;

__device__ __forceinline__ ushort f2bf(float f) {
    uint u = __builtin_bit_cast(uint, f);
    u += 0x7FFFu + ((u >> 16) & 1u);     // round-to-nearest-even
    return (ushort)(u >> 16);
}
__device__ __forceinline__ float bf2f(ushort h) {
    uint u = ((uint)h) << 16;
    return __builtin_bit_cast(float, u);
}

// ---------------------------------------------------------------------------
// k_init: zero hg + cnt, and bf16-pack conv weights into MFMA B layouts.
// Wtc[k][s][o][kl]  (3*12*96*32): w_k[o][i][t], kk=32s+kl, t=kk>>7, i=kk&127
// Wp1[k][s2][o][kl] (3*3*64*32) : W1k[kk2*54+o] (o<54), else 0
// ---------------------------------------------------------------------------
__global__ __launch_bounds__(256) void k_init(
    const float* __restrict__ w1, const float* __restrict__ w2,
    const float* __restrict__ w3,
    const float* __restrict__ W11, const float* __restrict__ W12,
    const float* __restrict__ W13,
    ushort* __restrict__ Wtc, ushort* __restrict__ Wp1,
    float* __restrict__ hg, int* __restrict__ cnt) {
    int idx = blockIdx.x * 256 + threadIdx.x;
    if (idx < N_GRAPHS * 49) hg[idx] = 0.f;
    if (idx < N_NODES) cnt[idx] = 0;
    if (idx < 3 * 12 * 96 * 32) {
        int kl = idx & 31;
        int o  = (idx >> 5) % 96;
        int s  = (idx >> 5) / 96 % 12;
        int k  = idx / (32 * 96 * 12);
        int kk = s * 32 + kl;
        int t = kk >> 7, i = kk & 127;
        const float* w = (k == 0) ? w1 : (k == 1) ? w2 : w3;
        Wtc[idx] = f2bf(w[(o * 128 + i) * 3 + t]);
    }
    if (idx < 3 * 3 * 64 * 32) {
        int kl = idx & 31;
        int o  = (idx >> 5) % 64;
        int s2 = (idx >> 5) / 64 % 3;
        int k  = idx / (32 * 64 * 3);
        int kk2 = s2 * 32 + kl;
        const float* W = (k == 0) ? W11 : (k == 1) ? W12 : W13;
        Wp1[idx] = (o < 54) ? f2bf(W[kk2 * 54 + o]) : (ushort)0;
    }
}

// ---------------------------------------------------------------------------
// CSR build: count -> multi-block scan -> scatter (packed int2 {src, w})
// ---------------------------------------------------------------------------
__global__ void k_count(const int* __restrict__ dst, int* __restrict__ cnt) {
    int e = blockIdx.x * blockDim.x + threadIdx.x;
    if (e < N_EDGES) atomicAdd(&cnt[dst[e]], 1);
}

__global__ __launch_bounds__(1024) void k_scan1(const int* __restrict__ cnt,
                                                int* __restrict__ cursor,
                                                int* __restrict__ bsum) {
    __shared__ int s[1024];
    int tid = threadIdx.x;
    int idx = blockIdx.x * 1024 + tid;      // 51200 = 50*1024 exactly
    int v = cnt[idx];
    s[tid] = v;
    __syncthreads();
    for (int off = 1; off < 1024; off <<= 1) {
        int t = s[tid];
        if (tid >= off) t += s[tid - off];
        __syncthreads();
        s[tid] = t;
        __syncthreads();
    }
    cursor[idx] = s[tid];
    if (tid == 1023) bsum[blockIdx.x] = s[1023];
}

__global__ void k_scan2(const int* __restrict__ bsum, int* __restrict__ boff) {
    if (threadIdx.x == 0 && blockIdx.x == 0) {
        int r = 0;
        for (int b = 0; b < 50; ++b) { boff[b] = r; r += bsum[b]; }
    }
}

__global__ __launch_bounds__(256) void k_scan3(const int* __restrict__ cnt,
                                               const int* __restrict__ boff,
                                               int* __restrict__ row_ptr,
                                               int* __restrict__ cursor) {
    int i = blockIdx.x * 256 + threadIdx.x;
    if (i < N_NODES) {
        int incl = cursor[i] + boff[i >> 10];
        row_ptr[i + 1] = incl;
        cursor[i] = incl - cnt[i];          // exclusive = row start
    }
    if (i == 0) row_ptr[0] = 0;
}

__global__ void k_scatter(const int* __restrict__ src, const int* __restrict__ dst,
                          const float* __restrict__ ew,
                          int* __restrict__ cursor, int2* __restrict__ s_pack) {
    int e = blockIdx.x * blockDim.x + threadIdx.x;
    if (e < N_EDGES) {
        int pos = atomicAdd(&cursor[dst[e]], 1);
        s_pack[pos] = make_int2(src[e], __float_as_int(ew[e]));
    }
}

// ---------------------------------------------------------------------------
// k_conv: 3 dilated convs as bf16 MFMA GEMMs; weights staged in LDS in TWO
// halves per conv (6 K-steps each) with register prefetch, so LDS = 55.9 KB
// -> 2 blocks/CU co-resident (one block's MFMAs hide the other's staging).
// Fused relu-combine + [96->54] epilogue -> hw_cat bf16 [N][176].
// ---------------------------------------------------------------------------
#define BN 64
#define XS_LD 136
#define HS_LD 104

__global__ __launch_bounds__(256, 2) void k_conv(
    const float* __restrict__ x,
    const ushort* __restrict__ Wtc, const ushort* __restrict__ Wp1g,
    const float* __restrict__ b1, const float* __restrict__ b2,
    const float* __restrict__ b3,
    ushort* __restrict__ hw_cat) {
    __shared__ ushort xs[70 * XS_LD];     // 9520 ushorts = 19040 B
    __shared__ ushort wl[18432];          // 36864 B: half-conv weights [6][96][32]
    ushort* wp   = wl;                    // epilogue weights alias (after conv)
    ushort* hswb = xs;                    // [4][16*HS_LD] = 6656 ushorts (alias xs)

    const int tid = threadIdx.x;
    const int n0  = blockIdx.x * BN;

    // stage x rows [n0-3, n0+67) as bf16, zero-padded ends
    for (int idx = tid; idx < 70 * 32; idx += 256) {
        int row = idx >> 5, c4 = (idx & 31) << 2;
        int node = n0 - 3 + row;
        float4 v = make_float4(0.f, 0.f, 0.f, 0.f);
        if (node >= 0 && node < N_NODES)
            v = *reinterpret_cast<const float4*>(x + (size_t)node * 128 + c4);
        ushort* p = &xs[row * XS_LD + c4];
        p[0] = f2bf(v.x); p[1] = f2bf(v.y); p[2] = f2bf(v.z); p[3] = f2bf(v.w);
    }

    const int lane = tid & 63;
    const int wave = tid >> 6;
    const int r16  = lane & 15;
    const int b8   = (lane >> 4) * 8;

    f32x4 acc[3][6];
#pragma unroll
    for (int k = 0; k < 3; ++k)
#pragma unroll
        for (int ot = 0; ot < 6; ++ot) acc[k][ot] = (f32x4)0.f;

    short8 wreg[9];
    short8 wpreg[9];
#pragma unroll
    for (int i = 0; i < 9; ++i)
        wreg[i] = *reinterpret_cast<const short8*>(Wtc + (size_t)(i * 256 + tid) * 8);

#pragma unroll
    for (int k = 0; k < 3; ++k) {
        const int dk = k + 1;
#pragma unroll
        for (int h = 0; h < 2; ++h) {
            __syncthreads();   // prior wl readers (or xs writers, first iter) done
#pragma unroll
            for (int i = 0; i < 9; ++i)
                *reinterpret_cast<short8*>(wl + (i * 256 + tid) * 8) = wreg[i];
            __syncthreads();
            const int hh = k * 2 + h;
            if (hh < 5) {      // prefetch next half under this half's MFMAs
                const ushort* nw = Wtc + (size_t)(hh + 1) * 18432;
#pragma unroll
                for (int i = 0; i < 9; ++i)
                    wreg[i] = *reinterpret_cast<const short8*>(nw + (size_t)(i * 256 + tid) * 8);
            } else {           // prefetch epilogue weights
#pragma unroll
                for (int i = 0; i < 9; ++i)
                    wpreg[i] = *reinterpret_cast<const short8*>(Wp1g + (size_t)(i * 256 + tid) * 8);
            }
#pragma unroll
            for (int sp = 0; sp < 6; ++sp) {
                const int s     = h * 6 + sp;
                const int cbase = (s * 32) & 127;
                const int t     = (s * 32) >> 7;
                const int roff  = (t - 1) * dk + 3;
                short8 a = *reinterpret_cast<const short8*>(
                    &xs[(wave * 16 + r16 + roff) * XS_LD + cbase + b8]);
#pragma unroll
                for (int ot = 0; ot < 6; ++ot) {
                    short8 b = *reinterpret_cast<const short8*>(
                        &wl[(sp * 96 + ot * 16 + r16) * 32 + b8]);
                    acc[k][ot] = __builtin_amdgcn_mfma_f32_16x16x32_bf16(a, b, acc[k][ot], 0, 0, 0);
                }
            }
        }
    }

    // bias + branch combine (in place)
#pragma unroll
    for (int ot = 0; ot < 6; ++ot) {
        int o = ot * 16 + r16;
        float bb1 = b1[o], bb2 = b2[o], bb3 = b3[o];
#pragma unroll
        for (int r = 0; r < 4; ++r) {
            float C1 = acc[0][ot][r] + bb1;
            float C2 = acc[1][ot][r] + bb2;
            float C3 = acc[2][ot][r] + bb3;
            acc[0][ot][r] = fmaxf(C1, 0.f) + C2;
            acc[1][ot][r] = fmaxf(C2, 0.f) + C3;
            acc[2][ot][r] = fmaxf(C3, 0.f) + C1;
        }
    }

    __syncthreads();           // conv reads of wl/xs done
#pragma unroll
    for (int i = 0; i < 9; ++i)
        *reinterpret_cast<short8*>(wp + (i * 256 + tid) * 8) = wpreg[i];

    // epilogue: hw_cat[:, 54k:54k+54] = h0k @ W1k  (MFMA, K=96)
    ushort* hs = hswb + wave * (16 * HS_LD);
#pragma unroll
    for (int k = 0; k < 3; ++k) {
        __syncthreads();
#pragma unroll
        for (int ot = 0; ot < 6; ++ot)
#pragma unroll
            for (int r = 0; r < 4; ++r)
                hs[((lane >> 4) * 4 + r) * HS_LD + ot * 16 + r16] = f2bf(acc[k][ot][r]);
        __syncthreads();
        f32x4 acc2[4];
#pragma unroll
        for (int ot2 = 0; ot2 < 4; ++ot2) acc2[ot2] = (f32x4)0.f;
#pragma unroll
        for (int s2 = 0; s2 < 3; ++s2) {
            short8 a = *reinterpret_cast<const short8*>(&hs[r16 * HS_LD + s2 * 32 + b8]);
#pragma unroll
            for (int ot2 = 0; ot2 < 4; ++ot2) {
                short8 b = *reinterpret_cast<const short8*>(
                    &wp[((k * 3 + s2) * 64 + ot2 * 16 + r16) * 32 + b8]);
                acc2[ot2] = __builtin_amdgcn_mfma_f32_16x16x32_bf16(a, b, acc2[ot2], 0, 0, 0);
            }
        }
#pragma unroll
        for (int ot2 = 0; ot2 < 4; ++ot2) {
            int co = ot2 * 16 + r16;
            if (co < 54) {
#pragma unroll
                for (int r = 0; r < 4; ++r) {
                    int node = n0 + wave * 16 + (lane >> 4) * 4 + r;
                    hw_cat[(size_t)node * 176 + k * 54 + co] = f2bf(acc2[ot2][r]);
                }
            }
        }
    }
    // zero pad cols 162..175 (don't rely on poison contents)
    for (int idx = tid; idx < 64 * 14; idx += 256) {
        int r = idx / 14, c = 162 + (idx - r * 14);
        hw_cat[(size_t)(n0 + r) * 176 + c] = 0;
    }
}

// ---------------------------------------------------------------------------
// k_agg1: CSR aggregate of hw_cat (bf16, 3x54) -> ac_h1 = sum relu(agg+b),
// fused with hw2 = ac_h1 @ W2 -> bf16 [N][28]. One wave per dst node;
// 4-edge unroll for load-level parallelism.
// ---------------------------------------------------------------------------
__global__ __launch_bounds__(256) void k_agg1(
    const ushort* __restrict__ hw, const int* __restrict__ row_ptr,
    const int2* __restrict__ pk,
    const float* __restrict__ b11, const float* __restrict__ b12,
    const float* __restrict__ b13, const float* __restrict__ W2,
    ushort* __restrict__ hw2) {
    __shared__ float stage[4][176];
    __shared__ float w2s[54 * 25];
    int tid = threadIdx.x;
    for (int i = tid; i < 54 * 25; i += 256) w2s[i] = W2[i];
    int lane = tid & 63, wave = tid >> 6;
    int n = blockIdx.x * 4 + wave;
    int e0 = row_ptr[n], e1 = row_ptr[n + 1];
    const bool act = lane < 44;
    const int col = lane * 4;
    float a0 = 0.f, a1 = 0.f, a2 = 0.f, a3 = 0.f;
    int e = e0;
    for (; e + 3 < e1; e += 4) {
        int2 m0 = pk[e], m1 = pk[e + 1], m2 = pk[e + 2], m3 = pk[e + 3];
        if (act) {
            ushort4 v0 = *reinterpret_cast<const ushort4*>(hw + (size_t)m0.x * 176 + col);
            ushort4 v1 = *reinterpret_cast<const ushort4*>(hw + (size_t)m1.x * 176 + col);
            ushort4 v2 = *reinterpret_cast<const ushort4*>(hw + (size_t)m2.x * 176 + col);
            ushort4 v3 = *reinterpret_cast<const ushort4*>(hw + (size_t)m3.x * 176 + col);
            float w0 = __int_as_float(m0.y), w1 = __int_as_float(m1.y);
            float w2 = __int_as_float(m2.y), w3 = __int_as_float(m3.y);
            a0 += w0 * bf2f(v0.x) + w1 * bf2f(v1.x) + w2 * bf2f(v2.x) + w3 * bf2f(v3.x);
            a1 += w0 * bf2f(v0.y) + w1 * bf2f(v1.y) + w2 * bf2f(v2.y) + w3 * bf2f(v3.y);
            a2 += w0 * bf2f(v0.z) + w1 * bf2f(v1.z) + w2 * bf2f(v2.z) + w3 * bf2f(v3.z);
            a3 += w0 * bf2f(v0.w) + w1 * bf2f(v1.w) + w2 * bf2f(v2.w) + w3 * bf2f(v3.w);
        }
    }
    for (; e < e1; ++e) {
        int2 m = pk[e];
        if (act) {
            ushort4 v = *reinterpret_cast<const ushort4*>(hw + (size_t)m.x * 176 + col);
            float w = __int_as_float(m.y);
            a0 += w * bf2f(v.x);
            a1 += w * bf2f(v.y);
            a2 += w * bf2f(v.z);
            a3 += w * bf2f(v.w);
        }
    }
    if (act) {
        float av[4] = {a0, a1, a2, a3};
#pragma unroll
        for (int j = 0; j < 4; ++j) {
            int f = col + j;
            float bias = (f < 54) ? b11[f] : (f < 108) ? b12[f - 54]
                        : (f < 162) ? b13[f - 108] : 0.f;
            stage[wave][f] = fmaxf(av[j] + bias, 0.f);
        }
    }
    __syncthreads();          // stage + w2s ready
    if (lane < 54)
        stage[wave][lane] = stage[wave][lane] + stage[wave][lane + 54] +
                            stage[wave][lane + 108];
    __syncthreads();
    if (lane < 25) {
        float acc = 0.f;
#pragma unroll
        for (int i = 0; i < 54; ++i) acc += stage[wave][i] * w2s[i * 25 + lane];
        hw2[(size_t)n * 28 + lane] = f2bf(acc);
    }
}

// ---------------------------------------------------------------------------
// k_agg2: aggregate hw2 (bf16) -> ac_h2 = relu(agg+b2); run-length-reduced
// seg-sum into hg[:,0:25]; fused hw34 = ac_h2 @ [W3|W4] -> bf16 [N][24].
// Two nodes per wave; 4-edge unroll.
// ---------------------------------------------------------------------------
__global__ __launch_bounds__(256) void k_agg2(
    const ushort* __restrict__ hw2, const int* __restrict__ row_ptr,
    const int2* __restrict__ pk,
    const float* __restrict__ b2, const float* __restrict__ W3,
    const float* __restrict__ W4, const int* __restrict__ gids,
    ushort* __restrict__ hw34, float* __restrict__ hg) {
    __shared__ float w34s[25 * 24];
    __shared__ float vst[8][26];
    __shared__ int sgid[8];
    int tid = threadIdx.x;
    for (int i = tid; i < 25 * 24; i += 256) {
        int ii = i / 24, j = i - ii * 24;
        w34s[i] = (j < 13) ? W3[ii * 13 + j] : W4[ii * 11 + (j - 13)];
    }
    int lane = tid & 63, wave = tid >> 6;
    int half = lane >> 5, jj = lane & 31;
    int n0b = blockIdx.x * 8;
    int nl = wave * 2 + half;
    int n = n0b + nl;
    int e0 = row_ptr[n], e1 = row_ptr[n + 1];
    float acc = 0.f;
    int e = e0;
    for (; e + 3 < e1; e += 4) {
        int2 m0 = pk[e], m1 = pk[e + 1], m2 = pk[e + 2], m3 = pk[e + 3];
        if (jj < 25)
            acc += __int_as_float(m0.y) * bf2f(hw2[(size_t)m0.x * 28 + jj]) +
                   __int_as_float(m1.y) * bf2f(hw2[(size_t)m1.x * 28 + jj]) +
                   __int_as_float(m2.y) * bf2f(hw2[(size_t)m2.x * 28 + jj]) +
                   __int_as_float(m3.y) * bf2f(hw2[(size_t)m3.x * 28 + jj]);
    }
    for (; e < e1; ++e) {
        int2 m = pk[e];
        if (jj < 25) acc += __int_as_float(m.y) * bf2f(hw2[(size_t)m.x * 28 + jj]);
    }
    if (jj < 25) {
        float v = fmaxf(acc + b2[jj], 0.f);
        vst[nl][jj] = v;
    }
    if (jj == 0) sgid[nl] = gids[n];
    __syncthreads();
    // run-length reduced seg-sum (graph_ids sorted -> few runs per block)
    if (tid < 25) {
        float run = vst[0][tid];
        int g = sgid[0];
        for (int nn = 1; nn < 8; ++nn) {
            if (sgid[nn] == g) run += vst[nn][tid];
            else { atomicAdd(&hg[g * 49 + tid], run); run = vst[nn][tid]; g = sgid[nn]; }
        }
        atomicAdd(&hg[g * 49 + tid], run);
    }
    // hw34 GEMV
    if (tid < 192) {
        int node = tid / 24, j = tid - node * 24;
        float a = 0.f;
#pragma unroll
        for (int i = 0; i < 25; ++i) a += vst[node][i] * w34s[i * 24 + j];
        hw34[(size_t)(n0b + node) * 24 + j] = f2bf(a);
    }
}

// ---------------------------------------------------------------------------
// k_agg34: aggregate hw34 (bf16) -> relu+bias, run-length seg-sum hg[:,25:49]
// ---------------------------------------------------------------------------
__global__ __launch_bounds__(256) void k_agg34(
    const ushort* __restrict__ hw34, const int* __restrict__ row_ptr,
    const int2* __restrict__ pk,
    const float* __restrict__ b3, const float* __restrict__ b4,
    const int* __restrict__ gids, float* __restrict__ hg) {
    __shared__ float vst[8][25];
    __shared__ int sgid[8];
    int tid = threadIdx.x;
    int lane = tid & 63, wave = tid >> 6;
    int half = lane >> 5, jj = lane & 31;
    int nl = wave * 2 + half;
    int n = blockIdx.x * 8 + nl;
    int e0 = row_ptr[n], e1 = row_ptr[n + 1];
    float acc = 0.f;
    int e = e0;
    for (; e + 3 < e1; e += 4) {
        int2 m0 = pk[e], m1 = pk[e + 1], m2 = pk[e + 2], m3 = pk[e + 3];
        if (jj < 24)
            acc += __int_as_float(m0.y) * bf2f(hw34[(size_t)m0.x * 24 + jj]) +
                   __int_as_float(m1.y) * bf2f(hw34[(size_t)m1.x * 24 + jj]) +
                   __int_as_float(m2.y) * bf2f(hw34[(size_t)m2.x * 24 + jj]) +
                   __int_as_float(m3.y) * bf2f(hw34[(size_t)m3.x * 24 + jj]);
    }
    for (; e < e1; ++e) {
        int2 m = pk[e];
        if (jj < 24) acc += __int_as_float(m.y) * bf2f(hw34[(size_t)m.x * 24 + jj]);
    }
    if (jj < 24) {
        float v = (jj < 13) ? fmaxf(acc + b3[jj], 0.f)
                            : fmaxf(acc + b4[jj - 13], 0.f);
        vst[nl][jj] = v;
    }
    if (jj == 0) sgid[nl] = gids[n];
    __syncthreads();
    if (tid < 24) {
        float run = vst[0][tid];
        int g = sgid[0];
        for (int nn = 1; nn < 8; ++nn) {
            if (sgid[nn] == g) run += vst[nn][tid];
            else { atomicAdd(&hg[g * 49 + 25 + tid], run); run = vst[nn][tid]; g = sgid[nn]; }
        }
        atomicAdd(&hg[g * 49 + 25 + tid], run);
    }
}

// ---------------------------------------------------------------------------
// k_final: out = (hg @ Wc1 + bc1) @ Wc2 + bc2     [256,49]->[256,5]
// ---------------------------------------------------------------------------
__global__ __launch_bounds__(256) void k_final(
    const float* __restrict__ hg, const float* __restrict__ Wc1,
    const float* __restrict__ bc1, const float* __restrict__ Wc2,
    const float* __restrict__ bc2, float* __restrict__ out) {
    int g = blockIdx.x * blockDim.x + threadIdx.x;
    if (g < N_GRAPHS) {
        float t[27];
#pragma unroll
        for (int j = 0; j < 27; ++j) t[j] = bc1[j];
        for (int i = 0; i < 49; ++i) {
            float hv = hg[g * 49 + i];
#pragma unroll
            for (int j = 0; j < 27; ++j) t[j] += hv * Wc1[i * 27 + j];
        }
#pragma unroll
        for (int j2 = 0; j2 < 5; ++j2) {
            float o = bc2[j2];
#pragma unroll
            for (int i = 0; i < 27; ++i) o += t[i] * Wc2[i * 5 + j2];
            out[g * 5 + j2] = o;
        }
    }
}

// ---------------------------------------------------------------------------
extern "C" void kernel_launch(void* const* d_in, const int* in_sizes, int n_in,
                              void* d_out, int out_size, void* d_ws, size_t ws_size,
                              hipStream_t stream) {
    const float* x    = (const float*)d_in[0];
    const int*   src  = (const int*)d_in[1];
    const int*   dst  = (const int*)d_in[2];
    const int*   gids = (const int*)d_in[3];
    const float* ew   = (const float*)d_in[4];
    const float* w1 = (const float*)d_in[5],  *b1 = (const float*)d_in[6];
    const float* w2 = (const float*)d_in[7],  *b2 = (const float*)d_in[8];
    const float* w3 = (const float*)d_in[9],  *b3 = (const float*)d_in[10];
    const float* W11 = (const float*)d_in[11], *b11 = (const float*)d_in[12];
    const float* W12 = (const float*)d_in[13], *b12 = (const float*)d_in[14];
    const float* W13 = (const float*)d_in[15], *b13 = (const float*)d_in[16];
    const float* W2  = (const float*)d_in[17], *b2g = (const float*)d_in[18];
    const float* W3  = (const float*)d_in[19], *b3g = (const float*)d_in[20];
    const float* W4  = (const float*)d_in[21], *b4g = (const float*)d_in[22];
    const float* Wc1 = (const float*)d_in[23], *bc1 = (const float*)d_in[24];
    const float* Wc2 = (const float*)d_in[25], *bc2 = (const float*)d_in[26];
    float* out = (float*)d_out;

    char* ws = (char*)d_ws;
    size_t off = 0;
    auto alloc = [&](size_t bytes) {
        size_t o = off;
        off = (off + bytes + 255) & ~(size_t)255;
        return (void*)(ws + o);
    };
    int*    cnt     = (int*)alloc(N_NODES * 4);
    int*    row_ptr = (int*)alloc((N_NODES + 1) * 4);
    int*    cursor  = (int*)alloc(N_NODES * 4);
    int*    bsum    = (int*)alloc(64 * 4);
    int*    boff    = (int*)alloc(64 * 4);
    int2*   s_pack  = (int2*)alloc((size_t)N_EDGES * 8);
    ushort* hw_cat  = (ushort*)alloc((size_t)N_NODES * 176 * 2);
    ushort* hw2     = (ushort*)alloc((size_t)N_NODES * 28 * 2);
    ushort* hw34    = (ushort*)alloc((size_t)N_NODES * 24 * 2);
    float*  hg      = (float*)alloc(N_GRAPHS * 49 * 4);
    ushort* Wtc     = (ushort*)alloc(3 * 12 * 96 * 32 * 2);
    ushort* Wp1     = (ushort*)alloc(3 * 3 * 64 * 32 * 2);

    k_init<<<(3 * 12 * 96 * 32 + 255) / 256, 256, 0, stream>>>(
        w1, w2, w3, W11, W12, W13, Wtc, Wp1, hg, cnt);
    k_count<<<N_EDGES / 256, 256, 0, stream>>>(dst, cnt);
    k_scan1<<<50, 1024, 0, stream>>>(cnt, cursor, bsum);
    k_scan2<<<1, 64, 0, stream>>>(bsum, boff);
    k_scan3<<<200, 256, 0, stream>>>(cnt, boff, row_ptr, cursor);
    k_scatter<<<N_EDGES / 256, 256, 0, stream>>>(src, dst, ew, cursor, s_pack);
    k_conv<<<N_NODES / BN, 256, 0, stream>>>(x, Wtc, Wp1, b1, b2, b3, hw_cat);
    k_agg1<<<N_NODES / 4, 256, 0, stream>>>(hw_cat, row_ptr, s_pack,
                                            b11, b12, b13, W2, hw2);
    k_agg2<<<N_NODES / 8, 256, 0, stream>>>(hw2, row_ptr, s_pack, b2g,
                                            W3, W4, gids, hw34, hg);
    k_agg34<<<N_NODES / 8, 256, 0, stream>>>(hw34, row_ptr, s_pack, b3g, b4g,
                                             gids, hg);
    k_final<<<1, 256, 0, stream>>>(hg, Wc1, bc1, Wc2, bc2, out);
}